// Round 3
// baseline (99.966 us; speedup 1.0000x reference)
//
#include <hip/hip_runtime.h>
#include <hip/hip_bf16.h>
#include <math.h>

#define BATCH 8
#define SEQ   2048
#define DIM   64
#define NEGC   (-1e9f)
// log2(e) and pre-scaled constants: scores are kept in log2 domain so the
// softmax exp is a bare v_exp_f32 (exp2) with no per-element multiply.
#define LOG2E  1.4426950408889634f
#define QSC    (LOG2E / 8.0f)          // 1/sqrt(64) folded with log2(e)
#define NEGC2  (-1.4426950408889634e9f) // NEGC * log2(e)

typedef short short8  __attribute__((ext_vector_type(8)));
typedef float f32x4   __attribute__((ext_vector_type(4)));
typedef float f32x16  __attribute__((ext_vector_type(16)));
typedef unsigned int uint2v __attribute__((ext_vector_type(2)));

#define MFMA32(a, b, c) __builtin_amdgcn_mfma_f32_32x32x16_bf16((a), (b), (c), 0, 0, 0)

__device__ __forceinline__ ushort f2bf(float x) {   // fp32 -> bf16 bits, RNE
    uint u = __float_as_uint(x);
    uint r = (u + 0x7fffu + ((u >> 16) & 1u)) >> 16;
    return (ushort)r;
}
__device__ __forceinline__ float bf2f(ushort h) {
    return __uint_as_float(((uint)h) << 16);
}

// ---------------------------------------------------------------------------
// ws layout (only first 4MB used):
//   KV frag images, per (b,tile) 16384 B = [Kh 8KB][Vf 8KB]
//     Kh row r (8 bf16, 16B): r=(mt*4+kc)*64+L ->
//        K[key=mt*32+(L&31)][d=kc*16+(L>>5)*8+j]     (A-frag for 32x32x16)
//     Vf row r: r=(dt*4+kc)*64+L ->
//        V[key=kc*16+(L>>5)*8+j][d=dt*32+(L&31)]     (A-frag, V pre-masked)
//
// Grid 512: blockIdx&7 = batch (XCD-affine, same mapping as attn_fused so
// the frag image lands in the L2 of the XCD that will read it).
// bit3..7: r = blockIdx>>3; tile = r&31 is wrong for K/V split; we use
// kv = (blockIdx>>3)>>5, tile = (blockIdx>>3)&31.
// ---------------------------------------------------------------------------
__global__ __launch_bounds__(256)
void prep_kv(const float* __restrict__ K, const float* __restrict__ V,
             const float* __restrict__ MV, ushort* __restrict__ ws) {
    __shared__ float raw[64 * 68];
    const int t    = threadIdx.x;
    const int b    = blockIdx.x & 7;
    const int rr   = blockIdx.x >> 3;      // 0..63
    const int tile = rr & 31;
    const int kv   = rr >> 5;              // 0 = K, 1 = V
    ushort* wsI = ws + (size_t)(b * 32 + tile) * 8192;

    if (kv == 0) {
        const float* Kb = K + ((size_t)b * SEQ + tile * 64) * DIM;
#pragma unroll
        for (int u = 0; u < 4; u++) {
            int f = t + 256 * u, key = f >> 4, d4 = (f & 15) * 4;
            *(float4*)&raw[key * 68 + d4] = *(const float4*)(Kb + (size_t)f * 4);
        }
        __syncthreads();
#pragma unroll
        for (int u = 0; u < 2; u++) {
            int r = t + 256 * u;
            int mt = r >> 8, kc = (r >> 6) & 3, L = r & 63;
            int key = mt * 32 + (L & 31), d0 = kc * 16 + (L >> 5) * 8;
            float4 x0 = *(float4*)&raw[key * 68 + d0];
            float4 x1 = *(float4*)&raw[key * 68 + d0 + 4];
            float xs[8] = {x0.x, x0.y, x0.z, x0.w, x1.x, x1.y, x1.z, x1.w};
            short8 hv;
#pragma unroll
            for (int j = 0; j < 8; j++) hv[j] = (short)f2bf(xs[j]);
            *(short8*)(wsI + r * 8) = hv;
        }
    } else {
        const float* Vb  = V  + ((size_t)b * SEQ + tile * 64) * DIM;
        const float* MVb = MV + (size_t)b * SEQ + tile * 64;
#pragma unroll
        for (int u = 0; u < 4; u++) {
            int f = t + 256 * u, key = f >> 4, d4 = (f & 15) * 4;
            float4 x = *(const float4*)(Vb + (size_t)f * 4);
            float mv = MVb[key];
            x.x *= mv; x.y *= mv; x.z *= mv; x.w *= mv;
            *(float4*)&raw[key * 68 + d4] = x;
        }
        __syncthreads();
#pragma unroll
        for (int u = 0; u < 2; u++) {
            int r = t + 256 * u;
            int dt = r >> 8, kc = (r >> 6) & 3, L = r & 63;
            int d = dt * 32 + (L & 31), k0 = kc * 16 + (L >> 5) * 8;
            short8 ov;
#pragma unroll
            for (int j = 0; j < 8; j++) ov[j] = (short)f2bf(raw[(k0 + j) * 68 + d]);
            *(short8*)(wsI + 4096 + r * 8) = ov;
        }
    }
}

// ---------------------------------------------------------------------------
// Fused main: 256 blocks (1/CU) x 512 thr = 8 waves (2 qg x 4 ks).
// Each wave: 32 q x 512 keys (16 chunks of 32 keys), frags loaded DIRECTLY
// from L2-resident ws images into registers (no LDS staging, no barriers in
// the main loop). 2-chunk register pipeline hides L2 latency. 4-way split-K
// merged in LDS at the end; O stored coalesced via LDS transpose.
// b = blockIdx.x & 7 -> one batch per XCD (KV working set 512KB, L2-fit).
// 32x32 C/D: col=lane&31, row=(reg&3)+8*(reg>>2)+4*(lane>>5).
// Softmax in log2 domain (Q pre-scaled by log2e/8) -> p = v_exp_f32 direct.
// ---------------------------------------------------------------------------
__global__ __launch_bounds__(512, 2)
void attn_fused(const float* __restrict__ Q, const float* __restrict__ MQ,
                const float* __restrict__ MK, const ushort* __restrict__ ws,
                float* __restrict__ O) {
    __shared__ __align__(16) float Msc[2][3][64][36];
    __shared__ __align__(16) float Oout[2][32][72];

    const int t    = threadIdx.x;
    const int w    = t >> 6;
    const int lane = t & 63;
    const int h    = lane >> 5;
    const int lm   = lane & 31;
    const int qg   = w & 1;        // query group (2 x 32q)
    const int ks   = w >> 1;       // k-split 0..3 (512 keys each)

    const int b  = blockIdx.x & 7;   // XCD-affine batch mapping
    const int qt = blockIdx.x >> 3;
    const int q  = qt * 64 + qg * 32 + lm;

    const float*  MKb = MK + (size_t)b * SEQ;
    const ushort* wsB = ws + (size_t)b * 32 * 8192;

    // ---- Q fragments (B-operand), hi/lo, pre-scaled by log2e/8 ----
    short8 qh[4], ql[4];
    {
        const float* Qr = Q + ((size_t)b * SEQ + q) * DIM;
#pragma unroll
        for (int kc = 0; kc < 4; kc++) {
            const float* p = Qr + kc * 16 + h * 8;
            float4 x0 = *(const float4*)p;
            float4 x1 = *(const float4*)(p + 4);
            float xs[8] = {x0.x, x0.y, x0.z, x0.w, x1.x, x1.y, x1.z, x1.w};
#pragma unroll
            for (int j = 0; j < 8; j++) {
                float v   = xs[j] * QSC;
                ushort hi = f2bf(v);
                ql[kc][j] = (short)f2bf(v - bf2f(hi));
                qh[kc][j] = (short)hi;
            }
        }
    }
    const float mq    = MQ[(size_t)b * SEQ + q];
    const float apen2 = NEGC2 * mq;

    float m = -1e30f, l = 0.0f;
    f32x16 ot0, ot1;
#pragma unroll
    for (int i = 0; i < 16; i++) { ot0[i] = 0.0f; ot1[i] = 0.0f; }

    // ---- register fragment loader: chunk ch = 32 keys ----
    // bias[v][c] = NEGC2 - apen2*mk  (log2 domain), off the critical path.
    auto loadch = [&](short8 (&kf)[4], short8 (&vf)[4], f32x4 (&bias)[4], int ch) {
        const int tt = ch >> 1, mt = ch & 1;
        const ushort* img = wsB + (size_t)tt * 8192;
#pragma unroll
        for (int kc = 0; kc < 4; kc++)
            kf[kc] = *(const short8*)(img + (((mt * 4 + kc) << 6) + lane) * 8);
#pragma unroll
        for (int u = 0; u < 4; u++) {
            const int dt = u >> 1, c = u & 1;
            vf[u] = *(const short8*)(img + 4096 + (((dt * 4 + mt * 2 + c) << 6) + lane) * 8);
        }
        const float* mkp = MKb + ch * 32 + h * 4;
#pragma unroll
        for (int v = 0; v < 4; v++) {
            f32x4 mk = *(const f32x4*)(mkp + v * 8);
#pragma unroll
            for (int c = 0; c < 4; c++) bias[v][c] = NEGC2 - apen2 * mk[c];
        }
    };

    // ---- one 32-key chunk: QK^T -> online softmax (log2) -> PV ----
    auto step = [&](const short8 (&kf)[4], const short8 (&vf)[4],
                    const f32x4 (&bias)[4]) {
        f32x16 st;
#pragma unroll
        for (int i = 0; i < 16; i++) st[i] = 0.0f;
        __builtin_amdgcn_s_setprio(1);
#pragma unroll
        for (int kc = 0; kc < 4; kc++) {
            st = MFMA32(kf[kc], qh[kc], st);
            st = MFMA32(kf[kc], ql[kc], st);
        }
        __builtin_amdgcn_s_setprio(0);

        float sv[16];
#pragma unroll
        for (int v = 0; v < 4; v++)
#pragma unroll
            for (int c = 0; c < 4; c++)
                sv[v * 4 + c] = st[v * 4 + c] + bias[v][c];
        // row max: v_max3-friendly tree (8 ops)
        float t0 = fmaxf(fmaxf(sv[0],  sv[1]),  sv[2]);
        float t1 = fmaxf(fmaxf(sv[3],  sv[4]),  sv[5]);
        float t2 = fmaxf(fmaxf(sv[6],  sv[7]),  sv[8]);
        float t3 = fmaxf(fmaxf(sv[9],  sv[10]), sv[11]);
        float t4 = fmaxf(fmaxf(sv[12], sv[13]), sv[14]);
        float cm = fmaxf(fmaxf(fmaxf(t0, t1), t2),
                         fmaxf(fmaxf(t3, t4), sv[15]));
        cm = fmaxf(cm, __shfl_xor(cm, 32));
        if (!__all(cm <= m)) {            // exact skip: no lane's max grew
            float nm    = fmaxf(m, cm);
            float alpha = exp2f(m - nm);
            m = nm;
            l *= alpha;
            ot0 *= alpha; ot1 *= alpha;
        }
        float p[16];
#pragma unroll
        for (int i = 0; i < 16; i++) p[i] = exp2f(sv[i] - m);
        // pairwise-tree sum
        float s0 = (p[0] + p[1]) + (p[2] + p[3]);
        float s1 = (p[4] + p[5]) + (p[6] + p[7]);
        float s2 = (p[8] + p[9]) + (p[10] + p[11]);
        float s3 = (p[12] + p[13]) + (p[14] + p[15]);
        float cs = (s0 + s1) + (s2 + s3);
        cs += __shfl_xor(cs, 32);
        l += cs;

        // ---- P: C-layout -> B-frags via v_permlane32_swap_b32 ----
        // swap(A,B): A' = {A.lo, B.lo_from_lane-32}, B' = {A.hi_from_lane+32, B.hi}
        uint g[4][2];
#pragma unroll
        for (int v = 0; v < 4; v++) {
            __hip_bfloat162 c0 = __float22bfloat162_rn(make_float2(p[v*4+0], p[v*4+1]));
            __hip_bfloat162 c1 = __float22bfloat162_rn(make_float2(p[v*4+2], p[v*4+3]));
            __builtin_memcpy(&g[v][0], &c0, 4);
            __builtin_memcpy(&g[v][1], &c1, 4);
        }
        uint2v ra = __builtin_amdgcn_permlane32_swap(g[0][0], g[1][0], false, false);
        uint2v rb = __builtin_amdgcn_permlane32_swap(g[0][1], g[1][1], false, false);
        uint2v rc = __builtin_amdgcn_permlane32_swap(g[2][0], g[3][0], false, false);
        uint2v rd = __builtin_amdgcn_permlane32_swap(g[2][1], g[3][1], false, false);
        uint pbw[2][4] = {{ra[0], rb[0], ra[1], rb[1]},
                          {rc[0], rd[0], rc[1], rd[1]}};

        __builtin_amdgcn_s_setprio(1);
#pragma unroll
        for (int c = 0; c < 2; c++) {
            short8 pb;
            __builtin_memcpy(&pb, &pbw[c][0], 16);
            ot0 = MFMA32(vf[c],     pb, ot0);
            ot1 = MFMA32(vf[2 + c], pb, ot1);
        }
        __builtin_amdgcn_s_setprio(0);
    };

    // ---- main loop: 16 chunks, 2-deep register pipeline, NO barriers ----
    short8 kA[4], vA[4], kB[4], vB[4];
    f32x4  bA[4], bB[4];
    const int ch0 = ks * 16;
    loadch(kA, vA, bA, ch0);
#pragma unroll 1
    for (int i = 0; i < 8; i++) {
        loadch(kB, vB, bB, ch0 + 2 * i + 1);
        step(kA, vA, bA);
        if (i < 7) loadch(kA, vA, bA, ch0 + 2 * i + 2);
        step(kB, vB, bB);
    }

    // ---- 4-way split-K merge in LDS ----
    if (ks != 0) {
        float* sc = &Msc[qg][ks - 1][lane][0];
#pragma unroll
        for (int i = 0; i < 4; i++) {
            f32x4 r0, r1;
#pragma unroll
            for (int c = 0; c < 4; c++) { r0[c] = ot0[i*4+c]; r1[c] = ot1[i*4+c]; }
            *(f32x4*)&sc[i * 4]      = r0;
            *(f32x4*)&sc[16 + i * 4] = r1;
        }
        sc[32] = m;
        sc[33] = l;
    }
    __syncthreads();
    if (ks == 0) {
#pragma unroll
        for (int pp = 0; pp < 3; pp++) {
            const float* sc = &Msc[qg][pp][lane][0];
            float mb = sc[32], lb = sc[33];
            float nm = fmaxf(m, mb);
            float fa = exp2f(m - nm), fb = exp2f(mb - nm);
            m = nm;
            l = l * fa + lb * fb;
#pragma unroll
            for (int i = 0; i < 16; i++) {
                ot0[i] = ot0[i] * fa + sc[i] * fb;
                ot1[i] = ot1[i] * fa + sc[16 + i] * fb;
            }
        }
        const float inv = 1.0f / l;
        // write normalized O^T fragments into LDS tile [q][d]
#pragma unroll
        for (int dt = 0; dt < 2; dt++)
#pragma unroll
            for (int rq = 0; rq < 4; rq++) {
                f32x4 r;
#pragma unroll
                for (int c = 0; c < 4; c++)
                    r[c] = (dt ? ot1[rq * 4 + c] : ot0[rq * 4 + c]) * inv;
                *(f32x4*)&Oout[qg][lm][dt * 32 + rq * 8 + h * 4] = r;
            }
    }
    __syncthreads();

    // ---- cooperative coalesced store: 64 q x 64 d ----
    float* Ob = O + ((size_t)b * SEQ + qt * 64) * DIM;
#pragma unroll
    for (int u = 0; u < 2; u++) {
        int f = t + 512 * u;                 // 0..1023
        int row = f >> 4, d4 = (f & 15) * 4;
        f32x4 val = *(const f32x4*)&Oout[row >> 5][row & 31][d4];
        *(f32x4*)(Ob + (size_t)row * DIM + d4) = val;
    }
}

extern "C" void kernel_launch(void* const* d_in, const int* in_sizes, int n_in,
                              void* d_out, int out_size, void* d_ws, size_t ws_size,
                              hipStream_t stream) {
    const float* Q  = (const float*)d_in[0];
    const float* K  = (const float*)d_in[1];
    const float* V  = (const float*)d_in[2];
    const float* MQ = (const float*)d_in[3];
    const float* MK = (const float*)d_in[4];
    const float* MV = (const float*)d_in[5];
    float* O = (float*)d_out;

    ushort* wsKV = (ushort*)d_ws;

    prep_kv   <<<dim3(512), dim3(256), 0, stream>>>(K, V, MV, wsKV);
    attn_fused<<<dim3(256), dim3(512), 0, stream>>>(Q, MQ, MK, wsKV, O);
}

// Round 4
// 96.992 us; speedup vs baseline: 1.0307x; 1.0307x over previous
//
#include <hip/hip_runtime.h>
#include <hip/hip_bf16.h>
#include <math.h>

#define BATCH 8
#define SEQ   2048
#define DIM   64
#define NEGC   (-1e9f)
// log2(e) and pre-scaled constants: scores kept in log2 domain so the
// softmax exp is a bare v_exp_f32 (exp2) with no per-element multiply.
#define LOG2E  1.4426950408889634f
#define QSC    (LOG2E / 8.0f)           // 1/sqrt(64) folded with log2(e)
#define NEGC2  (-1.4426950408889634e9f) // NEGC * log2(e)

typedef short short8  __attribute__((ext_vector_type(8)));
typedef float f32x4   __attribute__((ext_vector_type(4)));
typedef float f32x16  __attribute__((ext_vector_type(16)));
typedef unsigned int uint2v __attribute__((ext_vector_type(2)));

#define MFMA32(a, b, c) __builtin_amdgcn_mfma_f32_32x32x16_bf16((a), (b), (c), 0, 0, 0)

__device__ __forceinline__ ushort f2bf(float x) {   // fp32 -> bf16 bits, RNE
    uint u = __float_as_uint(x);
    uint r = (u + 0x7fffu + ((u >> 16) & 1u)) >> 16;
    return (ushort)r;
}
__device__ __forceinline__ float bf2f(ushort h) {
    return __uint_as_float(((uint)h) << 16);
}

// ---------------------------------------------------------------------------
// ws layout (only first 4MB used):
//   KV frag images, per (b,tile) 16384 B = [Kh 8KB][Vf 8KB]
//     Kh row r (8 bf16, 16B): r=(mt*4+kc)*64+L ->
//        K[key=mt*32+(L&31)][d=kc*16+(L>>5)*8+j]     (A-frag for 32x32x16)
//     Vf row r: r=(dt*4+kc)*64+L ->
//        V[key=kc*16+(L>>5)*8+j][d=dt*32+(L&31)]     (A-frag, V pre-masked)
//
// Grid 512: blockIdx&7 = batch (XCD-affine, same mapping as attn_fused so
// the frag image lands in the L2 of the XCD that will read it).
// ---------------------------------------------------------------------------
__global__ __launch_bounds__(256)
void prep_kv(const float* __restrict__ K, const float* __restrict__ V,
             const float* __restrict__ MV, ushort* __restrict__ ws) {
    __shared__ float raw[64 * 68];
    const int t    = threadIdx.x;
    const int b    = blockIdx.x & 7;
    const int rr   = blockIdx.x >> 3;      // 0..63
    const int tile = rr & 31;
    const int kv   = rr >> 5;              // 0 = K, 1 = V
    ushort* wsI = ws + (size_t)(b * 32 + tile) * 8192;

    if (kv == 0) {
        const float* Kb = K + ((size_t)b * SEQ + tile * 64) * DIM;
#pragma unroll
        for (int u = 0; u < 4; u++) {
            int f = t + 256 * u, key = f >> 4, d4 = (f & 15) * 4;
            *(float4*)&raw[key * 68 + d4] = *(const float4*)(Kb + (size_t)f * 4);
        }
        __syncthreads();
#pragma unroll
        for (int u = 0; u < 2; u++) {
            int r = t + 256 * u;
            int mt = r >> 8, kc = (r >> 6) & 3, L = r & 63;
            int key = mt * 32 + (L & 31), d0 = kc * 16 + (L >> 5) * 8;
            float4 x0 = *(float4*)&raw[key * 68 + d0];
            float4 x1 = *(float4*)&raw[key * 68 + d0 + 4];
            float xs[8] = {x0.x, x0.y, x0.z, x0.w, x1.x, x1.y, x1.z, x1.w};
            short8 hv;
#pragma unroll
            for (int j = 0; j < 8; j++) hv[j] = (short)f2bf(xs[j]);
            *(short8*)(wsI + r * 8) = hv;
        }
    } else {
        const float* Vb  = V  + ((size_t)b * SEQ + tile * 64) * DIM;
        const float* MVb = MV + (size_t)b * SEQ + tile * 64;
#pragma unroll
        for (int u = 0; u < 4; u++) {
            int f = t + 256 * u, key = f >> 4, d4 = (f & 15) * 4;
            float4 x = *(const float4*)(Vb + (size_t)f * 4);
            float mv = MVb[key];
            x.x *= mv; x.y *= mv; x.z *= mv; x.w *= mv;
            *(float4*)&raw[key * 68 + d4] = x;
        }
        __syncthreads();
#pragma unroll
        for (int u = 0; u < 2; u++) {
            int r = t + 256 * u;
            int dt = r >> 8, kc = (r >> 6) & 3, L = r & 63;
            int d = dt * 32 + (L & 31), k0 = kc * 16 + (L >> 5) * 8;
            short8 ov;
#pragma unroll
            for (int j = 0; j < 8; j++) ov[j] = (short)f2bf(raw[(k0 + j) * 68 + d]);
            *(short8*)(wsI + 4096 + r * 8) = ov;
        }
    }
}

// ---------------------------------------------------------------------------
// Fused main: 256 blocks (1/CU) x 512 thr = 8 waves (2 qg x 4 ks).
// Each wave: 32 q x 512 keys (16 chunks of 32 keys), frags loaded DIRECTLY
// from L2-resident ws images into registers (no LDS staging, no main-loop
// barriers). Dual pipeline: smpv(chunk c) [softmax VALU + PV] runs in the
// shadow of qkt(chunk c+1)'s 8-MFMA cluster; loads issued 1.5-2 stages
// ahead. 4-way split-K merged in LDS at the end; coalesced store via LDS
// transpose. b = blockIdx.x&7 -> one batch per XCD (KV image L2-resident).
// 32x32 C/D: col=lane&31, row=(reg&3)+8*(reg>>2)+4*(lane>>5).
// ---------------------------------------------------------------------------
__global__ __launch_bounds__(512, 2)
void attn_fused(const float* __restrict__ Q, const float* __restrict__ MQ,
                const float* __restrict__ MK, const ushort* __restrict__ ws,
                float* __restrict__ O) {
    __shared__ __align__(16) float Msc[2][3][64][36];
    __shared__ __align__(16) float Oout[2][32][72];

    const int t    = threadIdx.x;
    const int w    = t >> 6;
    const int lane = t & 63;
    const int h    = lane >> 5;
    const int lm   = lane & 31;
    const int qg   = w & 1;        // query group (2 x 32q)
    const int ks   = w >> 1;       // k-split 0..3 (512 keys each)

    const int b  = blockIdx.x & 7;   // XCD-affine batch mapping
    const int qt = blockIdx.x >> 3;
    const int q  = qt * 64 + qg * 32 + lm;

    const float*  MKb = MK + (size_t)b * SEQ;
    const ushort* wsB = ws + (size_t)b * 32 * 8192;

    // ---- Q fragments (B-operand), hi/lo, pre-scaled by log2e/8 ----
    short8 qh[4], ql[4];
    {
        const float* Qr = Q + ((size_t)b * SEQ + q) * DIM;
#pragma unroll
        for (int kc = 0; kc < 4; kc++) {
            const float* p = Qr + kc * 16 + h * 8;
            float4 x0 = *(const float4*)p;
            float4 x1 = *(const float4*)(p + 4);
            float xs[8] = {x0.x, x0.y, x0.z, x0.w, x1.x, x1.y, x1.z, x1.w};
#pragma unroll
            for (int j = 0; j < 8; j++) {
                float v   = xs[j] * QSC;
                ushort hi = f2bf(v);
                ql[kc][j] = (short)f2bf(v - bf2f(hi));
                qh[kc][j] = (short)hi;
            }
        }
    }
    const float mq    = MQ[(size_t)b * SEQ + q];
    const float apen2 = NEGC2 * mq;

    float m = -1e30f, l = 0.0f;
    f32x16 ot0, ot1;
#pragma unroll
    for (int i = 0; i < 16; i++) { ot0[i] = 0.0f; ot1[i] = 0.0f; }

    // ---- loaders: K-frag (qkt operand) and V-frag+bias (smpv operands) ----
    auto loadK = [&](short8 (&kf)[4], int ch) {
        const int tt = ch >> 1, mt = ch & 1;
        const ushort* img = wsB + (size_t)tt * 8192;
#pragma unroll
        for (int kc = 0; kc < 4; kc++)
            kf[kc] = *(const short8*)(img + (((mt * 4 + kc) << 6) + lane) * 8);
    };
    auto loadVB = [&](short8 (&vf)[4], f32x4 (&bias)[4], int ch) {
        const int tt = ch >> 1, mt = ch & 1;
        const ushort* img = wsB + (size_t)tt * 8192;
#pragma unroll
        for (int u = 0; u < 4; u++) {
            const int dt = u >> 1, c = u & 1;
            vf[u] = *(const short8*)(img + 4096 + (((dt * 4 + mt * 2 + c) << 6) + lane) * 8);
        }
        const float* mkp = MKb + ch * 32 + h * 4;
#pragma unroll
        for (int v = 0; v < 4; v++) {
            f32x4 mk = *(const f32x4*)(mkp + v * 8);
#pragma unroll
            for (int c = 0; c < 4; c++) bias[v][c] = NEGC2 - apen2 * mk[c];
        }
    };

    // ---- QK^T: pure-MFMA cluster (issued, then VALU runs under it) ----
    auto qkt = [&](f32x16& st, const short8 (&kf)[4]) {
        f32x16 s;
#pragma unroll
        for (int i = 0; i < 16; i++) s[i] = 0.0f;
        __builtin_amdgcn_s_setprio(1);
#pragma unroll
        for (int kc = 0; kc < 4; kc++) {
            s = MFMA32(kf[kc], qh[kc], s);
            s = MFMA32(kf[kc], ql[kc], s);
        }
        __builtin_amdgcn_s_setprio(0);
        st = s;
    };

    // ---- softmax (log2 domain) + PV for one 32-key chunk ----
    auto smpv = [&](const f32x16& st, const short8 (&vf)[4],
                    const f32x4 (&bias)[4]) {
        float sv[16];
#pragma unroll
        for (int v = 0; v < 4; v++)
#pragma unroll
            for (int c = 0; c < 4; c++)
                sv[v * 4 + c] = st[v * 4 + c] + bias[v][c];
        // row max: v_max3-friendly tree
        float t0 = fmaxf(fmaxf(sv[0],  sv[1]),  sv[2]);
        float t1 = fmaxf(fmaxf(sv[3],  sv[4]),  sv[5]);
        float t2 = fmaxf(fmaxf(sv[6],  sv[7]),  sv[8]);
        float t3 = fmaxf(fmaxf(sv[9],  sv[10]), sv[11]);
        float t4 = fmaxf(fmaxf(sv[12], sv[13]), sv[14]);
        float cm = fmaxf(fmaxf(fmaxf(t0, t1), t2),
                         fmaxf(fmaxf(t3, t4), sv[15]));
        cm = fmaxf(cm, __shfl_xor(cm, 32));
        if (!__all(cm <= m)) {            // exact skip: no lane's max grew
            float nm    = fmaxf(m, cm);
            float alpha = exp2f(m - nm);
            m = nm;
            l *= alpha;
            ot0 *= alpha; ot1 *= alpha;
        }
        float p[16];
#pragma unroll
        for (int i = 0; i < 16; i++) p[i] = exp2f(sv[i] - m);
        float s0 = (p[0] + p[1]) + (p[2] + p[3]);
        float s1 = (p[4] + p[5]) + (p[6] + p[7]);
        float s2 = (p[8] + p[9]) + (p[10] + p[11]);
        float s3 = (p[12] + p[13]) + (p[14] + p[15]);
        float cs = (s0 + s1) + (s2 + s3);
        cs += __shfl_xor(cs, 32);
        l += cs;

        // ---- P: C-layout -> B-frags via v_permlane32_swap_b32 ----
        uint g[4][2];
#pragma unroll
        for (int v = 0; v < 4; v++) {
            __hip_bfloat162 c0 = __float22bfloat162_rn(make_float2(p[v*4+0], p[v*4+1]));
            __hip_bfloat162 c1 = __float22bfloat162_rn(make_float2(p[v*4+2], p[v*4+3]));
            __builtin_memcpy(&g[v][0], &c0, 4);
            __builtin_memcpy(&g[v][1], &c1, 4);
        }
        uint2v ra = __builtin_amdgcn_permlane32_swap(g[0][0], g[1][0], false, false);
        uint2v rb = __builtin_amdgcn_permlane32_swap(g[0][1], g[1][1], false, false);
        uint2v rc = __builtin_amdgcn_permlane32_swap(g[2][0], g[3][0], false, false);
        uint2v rd = __builtin_amdgcn_permlane32_swap(g[2][1], g[3][1], false, false);
        uint pbw[2][4] = {{ra[0], rb[0], ra[1], rb[1]},
                          {rc[0], rd[0], rc[1], rd[1]}};

        __builtin_amdgcn_s_setprio(1);
#pragma unroll
        for (int c = 0; c < 2; c++) {
            short8 pb;
            __builtin_memcpy(&pb, &pbw[c][0], 16);
            ot0 = MFMA32(vf[c],     pb, ot0);
            ot1 = MFMA32(vf[2 + c], pb, ot1);
        }
        __builtin_amdgcn_s_setprio(0);
    };

    // ---- main loop: 16 chunks, dual pipeline, NO barriers ----
    // Slot A holds even chunks, slot B odd. Invariant at iteration top:
    //   stA = qkt(2i), A has V/bias(2i), B has K(2i+1).
    short8 kA[4], vA[4], kB[4], vB[4];
    f32x4  bA[4], bB[4];
    f32x16 stA, stB;
    const int ch0 = ks * 16;
    loadK(kA, ch0); loadVB(vA, bA, ch0); loadK(kB, ch0 + 1);
    qkt(stA, kA);
#pragma unroll 1
    for (int i = 0; i < 7; i++) {
        loadVB(vB, bB, ch0 + 2 * i + 1);
        qkt(stB, kB);                      // MFMAs for chunk 2i+1 in flight
        loadK(kA, ch0 + 2 * i + 2);
        smpv(stA, vA, bA);                 // softmax 2i under qkt(2i+1)
        loadVB(vA, bA, ch0 + 2 * i + 2);
        qkt(stA, kA);                      // MFMAs for chunk 2i+2 in flight
        loadK(kB, ch0 + 2 * i + 3);
        smpv(stB, vB, bB);                 // softmax 2i+1 under qkt(2i+2)
    }
    loadVB(vB, bB, ch0 + 15);
    qkt(stB, kB);
    smpv(stA, vA, bA);                     // chunk 14
    smpv(stB, vB, bB);                     // chunk 15

    // ---- 4-way split-K merge in LDS ----
    if (ks != 0) {
        float* sc = &Msc[qg][ks - 1][lane][0];
#pragma unroll
        for (int i = 0; i < 4; i++) {
            f32x4 r0, r1;
#pragma unroll
            for (int c = 0; c < 4; c++) { r0[c] = ot0[i*4+c]; r1[c] = ot1[i*4+c]; }
            *(f32x4*)&sc[i * 4]      = r0;
            *(f32x4*)&sc[16 + i * 4] = r1;
        }
        sc[32] = m;
        sc[33] = l;
    }
    __syncthreads();
    if (ks == 0) {
#pragma unroll
        for (int pp = 0; pp < 3; pp++) {
            const float* sc = &Msc[qg][pp][lane][0];
            float mb = sc[32], lb = sc[33];
            float nm = fmaxf(m, mb);
            float fa = exp2f(m - nm), fb = exp2f(mb - nm);
            m = nm;
            l = l * fa + lb * fb;
#pragma unroll
            for (int i = 0; i < 16; i++) {
                ot0[i] = ot0[i] * fa + sc[i] * fb;
                ot1[i] = ot1[i] * fa + sc[16 + i] * fb;
            }
        }
        const float inv = 1.0f / l;
        // write normalized O^T fragments into LDS tile [q][d]
#pragma unroll
        for (int dt = 0; dt < 2; dt++)
#pragma unroll
            for (int rq = 0; rq < 4; rq++) {
                f32x4 r;
#pragma unroll
                for (int c = 0; c < 4; c++)
                    r[c] = (dt ? ot1[rq * 4 + c] : ot0[rq * 4 + c]) * inv;
                *(f32x4*)&Oout[qg][lm][dt * 32 + rq * 8 + h * 4] = r;
            }
    }
    __syncthreads();

    // ---- cooperative coalesced store: 64 q x 64 d ----
    float* Ob = O + ((size_t)b * SEQ + qt * 64) * DIM;
#pragma unroll
    for (int u = 0; u < 2; u++) {
        int f = t + 512 * u;                 // 0..1023
        int row = f >> 4, d4 = (f & 15) * 4;
        f32x4 val = *(const f32x4*)&Oout[row >> 5][row & 31][d4];
        *(f32x4*)(Ob + (size_t)row * DIM + d4) = val;
    }
}

extern "C" void kernel_launch(void* const* d_in, const int* in_sizes, int n_in,
                              void* d_out, int out_size, void* d_ws, size_t ws_size,
                              hipStream_t stream) {
    const float* Q  = (const float*)d_in[0];
    const float* K  = (const float*)d_in[1];
    const float* V  = (const float*)d_in[2];
    const float* MQ = (const float*)d_in[3];
    const float* MK = (const float*)d_in[4];
    const float* MV = (const float*)d_in[5];
    float* O = (float*)d_out;

    ushort* wsKV = (ushort*)d_ws;

    prep_kv   <<<dim3(512), dim3(256), 0, stream>>>(K, V, MV, wsKV);
    attn_fused<<<dim3(256), dim3(512), 0, stream>>>(Q, MQ, MK, wsKV, O);
}